// Round 20
// baseline (572.737 us; speedup 1.0000x reference)
//
#include <hip/hip_runtime.h>
#include <hip/hip_bf16.h>
#include <math.h>

typedef short v8s __attribute__((ext_vector_type(8)));
typedef float v4f __attribute__((ext_vector_type(4)));
typedef unsigned int v2u __attribute__((ext_vector_type(2)));
typedef __hip_bfloat16 bf16;

#define LDQK 1056   // qkb leading dim: 2112B row stride (breaks 2KB channel hotspot)
#define LDVT 2080   // vt row stride: 4160B (breaks 4KB)

__device__ inline short f2b(float f){
  __hip_bfloat16 h = __float2bfloat16(f);
  return __builtin_bit_cast(short, h);
}
// truncation pack for hot loop: P in [0,1], trunc error <= 2^-9 relative
__device__ inline unsigned int pack2t(float x, float y){
  unsigned int xb = __builtin_bit_cast(unsigned int, x);
  unsigned int yb = __builtin_bit_cast(unsigned int, y);
  return (xb >> 16) | (yb & 0xFFFF0000u);
}
__device__ inline v4f v4f_zero(){ v4f z = {0.f,0.f,0.f,0.f}; return z; }

__device__ inline void gload_lds16(const void* g, void* l){
  __builtin_amdgcn_global_load_lds(
      (__attribute__((address_space(1))) void*)(g),
      (__attribute__((address_space(3))) void*)(l), 16, 0, 0);
}

// ---------------- fp32 -> bf16 convert: all 7 tensors in ONE launch ----------------
struct CvtSeg { const float* s; bf16* d; int n4; };
struct CvtArgs { CvtSeg seg[7]; };

__global__ __launch_bounds__(256) void k_cvt7(CvtArgs a){
  const CvtSeg sg = a.seg[blockIdx.y];
  int i = blockIdx.x*256 + threadIdx.x;
  const int stride = gridDim.x*256;
  for (; i < sg.n4; i += stride){
    float4 v = ((const float4*)sg.s)[i];
    short4 o;
    o.x = f2b(v.x); o.y = f2b(v.y); o.z = f2b(v.z); o.w = f2b(v.w);
    ((short4*)sg.d)[i] = o;
  }
}

// ---------------- LayerNorm: one wave per row of 512, fp32 in -> bf16 out ----------------
__global__ __launch_bounds__(256) void k_ln(const float* __restrict__ x,
                                            const float* __restrict__ w,
                                            const float* __restrict__ b,
                                            bf16* __restrict__ out){
  const int row  = blockIdx.x*4 + (threadIdx.x>>6);
  const int lane = threadIdx.x & 63;
  const float* xr = x + (size_t)row*512 + lane*8;
  float4 a = *(const float4*)xr;
  float4 c = *(const float4*)(xr+4);
  float s  = a.x+a.y+a.z+a.w + c.x+c.y+c.z+c.w;
  float sq = a.x*a.x+a.y*a.y+a.z*a.z+a.w*a.w + c.x*c.x+c.y*c.y+c.z*c.z+c.w*c.w;
  #pragma unroll
  for (int m=1;m<64;m<<=1){ s += __shfl_xor(s,m); sq += __shfl_xor(sq,m); }
  const float mean = s*(1.f/512.f);
  const float rstd = rsqrtf(sq*(1.f/512.f) - mean*mean + 1e-5f);
  const float* wp = w + lane*8; const float* bp = b + lane*8;
  float4 w0 = *(const float4*)wp, w1v = *(const float4*)(wp+4);
  float4 b0 = *(const float4*)bp, b1v = *(const float4*)(bp+4);
  v8s o;
  o[0]=f2b((a.x-mean)*rstd*w0.x +b0.x);
  o[1]=f2b((a.y-mean)*rstd*w0.y +b0.y);
  o[2]=f2b((a.z-mean)*rstd*w0.z +b0.z);
  o[3]=f2b((a.w-mean)*rstd*w0.w +b0.w);
  o[4]=f2b((c.x-mean)*rstd*w1v.x+b1v.x);
  o[5]=f2b((c.y-mean)*rstd*w1v.y+b1v.y);
  o[6]=f2b((c.z-mean)*rstd*w1v.z+b1v.z);
  o[7]=f2b((c.w-mean)*rstd*w1v.w+b1v.w);
  *(v8s*)(out + (size_t)row*512 + lane*8) = o;
}

// ---------------- GEMM: C[M,N] = A[M,K] * W[N,K]^T + bias, fused epilogues ----------------
enum { EPI_F32=0, EPI_BF16=1, EPI_F32RES=2, EPI_GELU=3, EPI_VT=4, EPI_QKV=5 };

template<int BM, int BN, int BK, int WR, int EPI>
__global__ __launch_bounds__(256) void k_gemm(
    const bf16* __restrict__ A, const bf16* __restrict__ W,
    const float* __restrict__ bias,
    float* __restrict__ resf, bf16* __restrict__ outb,
    const int M, const int N, const int K, const int ldo)
{
  constexpr int WC = 4/WR;
  constexpr int FM = BM/(WR*16);
  constexpr int FN = BN/(WC*16);
  constexpr int KK = BK/32;
  constexpr int CPR = BK/8;             // 16B chunks per row of a K-step
  __shared__ __align__(16) bf16 As[2][BM*BK];
  __shared__ __align__(16) bf16 Bs[2][BN*BK];
  const int tid  = threadIdx.x;
  const int wave = tid>>6, lane = tid&63;
  const int r = lane&15, g = lane>>4;
  const int bm = blockIdx.x*BM, bn = blockIdx.y*BN;
  const int wr = (WR==1) ? 0 : (wave>>1);
  const int wc = (WR==1) ? wave : (wave&1);

  v4f acc[FM][FN];
  #pragma unroll
  for (int i=0;i<FM;++i)
    #pragma unroll
    for (int j=0;j<FN;++j) acc[i][j] = v4f_zero();

  const int NT = K / BK;

  auto stage = [&](int buf, int kb){
    constexpr int ACH = BM*CPR;
    #pragma unroll
    for (int it=0; it<(ACH+255)/256; ++it){
      const int cb = it*256 + wave*64;
      if ((ACH & 255) == 0 || cb < ACH){
        const int cc = cb + lane;
        const bf16* gp = A + (size_t)(bm + cc/CPR)*K + kb + (cc%CPR)*8;
        gload_lds16(gp, &As[buf][cc*8]);
      }
    }
    constexpr int BCH = BN*CPR;
    #pragma unroll
    for (int it=0; it<(BCH+255)/256; ++it){
      const int cb = it*256 + wave*64;
      if ((BCH & 255) == 0 || cb < BCH){
        const int cc = cb + lane;
        const bf16* gp = W + (size_t)(bn + cc/CPR)*K + kb + (cc%CPR)*8;
        gload_lds16(gp, &Bs[buf][cc*8]);
      }
    }
  };

  stage(0, 0);
  int cur = 0;
  for (int t=0; t<NT; ++t){
    __syncthreads();
    if (t+1 < NT) stage(cur^1, (t+1)*BK);
    const bf16* ap = &As[cur][(wr*(BM/WR) + r)*BK + g*8];
    const bf16* bp = &Bs[cur][(wc*(BN/WC) + r)*BK + g*8];
    #pragma unroll
    for (int kk=0; kk<KK; ++kk){
      v8s af[FM], bfr[FN];
      #pragma unroll
      for (int i=0;i<FM;++i) af[i] = *(const v8s*)(ap + i*16*BK + kk*32);
      #pragma unroll
      for (int j=0;j<FN;++j) bfr[j] = *(const v8s*)(bp + j*16*BK + kk*32);
      #pragma unroll
      for (int i=0;i<FM;++i)
        #pragma unroll
        for (int j=0;j<FN;++j)
          acc[i][j] = __builtin_amdgcn_mfma_f32_16x16x32_bf16(af[i], bfr[j], acc[i][j], 0,0,0);
    }
    cur ^= 1;
  }

  #pragma unroll
  for (int j=0;j<FN;++j){
    const int col = bn + wc*(BN/WC) + j*16 + r;
    const float bv = bias[col];
    #pragma unroll
    for (int i=0;i<FM;++i){
      const int row0 = bm + wr*(BM/WR) + i*16 + g*4;
      if constexpr (EPI==EPI_QKV){
        // fused QK+V projection: cols 0..1023 -> qkb (padded LDQK rows),
        // cols 1024..1535 -> Vt[b][h][d][s] (row stride LDVT). resf = (float*)vtb.
        if (col < 1024){
          #pragma unroll
          for (int q=0;q<4;++q)
            outb[(size_t)(row0+q)*LDQK + col] = __float2bfloat16(acc[i][j][q] + bv);
        } else {
          const int d = col - 1024;
          bf16* vt = (bf16*)resf
                   + (((size_t)(row0>>11)*8 + (d>>6))*64 + (d&63))*(size_t)LDVT + (row0&2047);
          short4 st;
          st.x = f2b(acc[i][j][0] + bv);
          st.y = f2b(acc[i][j][1] + bv);
          st.z = f2b(acc[i][j][2] + bv);
          st.w = f2b(acc[i][j][3] + bv);
          *(short4*)vt = st;
        }
      } else if constexpr (EPI==EPI_VT){
        bf16* vt = outb + (((size_t)(row0>>11)*8 + (col>>6))*64 + (col&63))*(size_t)ldo + (row0&2047);
        short4 st;
        st.x = f2b(acc[i][j][0] + bv);
        st.y = f2b(acc[i][j][1] + bv);
        st.z = f2b(acc[i][j][2] + bv);
        st.w = f2b(acc[i][j][3] + bv);
        *(short4*)vt = st;
      } else {
        #pragma unroll
        for (int q=0;q<4;++q){
          float v = acc[i][j][q] + bv;
          const size_t idx = (size_t)(row0+q)*ldo + col;
          if constexpr (EPI==EPI_F32)         resf[idx] = v;
          else if constexpr (EPI==EPI_F32RES) resf[idx] += v;
          else if constexpr (EPI==EPI_BF16)   outb[idx] = __float2bfloat16(v);
          else if constexpr (EPI==EPI_GELU){
            float gv = 0.5f*v*(1.f + erff(v*0.70710678118654752f));
            outb[idx] = __float2bfloat16(gv);
          }
        }
      }
    }
  }
}

// ---------------- causal + ALiBi flash attention: 4 q-subtiles/block (L2-read amortization) ----------------
// qk: [B,S,LDQK], vt: [B,NH,64,LDVT], o: [B,S,512]
// grid 512: flat = qi*16 + b*8 + h -> XCD(flat%8)=h. qi in 0..31.
// Block = 4 q-subtiles {qi, 63-qi, 64+qi, 127-qi}: k-ranges nested, sum nt = 130
// (constant -> balanced). One K/V fragment set per k-tile now feeds up to FOUR
// processU calls (~2.2x load amortization vs ~1.03 in the pair structure) ->
// ~1.7x fewer scattered L2 reads (est. 12 TB/s -> 7; theory: L2-request-bound).
// Fixed-max softmax; K AND V register-double-buffered; pack2t P-pack.
__global__ __launch_bounds__(256) void k_attn(const bf16* __restrict__ qk,
                                              const bf16* __restrict__ vt,
                                              bf16* __restrict__ o){
  const int flat  = blockIdx.x;
  const int qi    = flat >> 4;          // 0..31
  const int head  = flat & 7;
  const int batch = (flat >> 3) & 1;
  const int sp = threadIdx.x>>6, lane = threadIdx.x&63;
  const int r = lane&15, g = lane>>4;
  const float LOG2E = 1.4426950408889634f;
  const float scale2 = 0.125f * LOG2E;
  const float slope2 = exp2f(-(float)(head+1)) * LOG2E;
  const bf16* qbase = qk + (size_t)batch*2048*LDQK + head*64;
  const bf16* kbase = qbase + 512;
  const bf16* vbase = vt + (size_t)(batch*8 + head)*64*LDVT;

  __shared__ float Ls[4][4][16];
  __shared__ __align__(16) v4f Os[4][4][64];       // 16 KB, reused across 4 merge phases
  __shared__ __align__(16) short Psw[4][16][40];   // padded: row stride 80B

  const int w0 = qi, w1 = 63-qi, w2 = 64+qi, w3 = 127-qi;
  const int nt0 = (w0>>1)+1, nt1 = (w1>>1)+1, nt2 = (w2>>1)+1, nt3 = (w3>>1)+1;
  const int q0 = w0*16 + r, q1 = w1*16 + r, q2 = w2*16 + r, q3 = w3*16 + r;

  const bf16* q0p = qbase + (size_t)q0*LDQK + g*8;
  const bf16* q1p = qbase + (size_t)q1*LDQK + g*8;
  const bf16* q2p = qbase + (size_t)q2*LDQK + g*8;
  const bf16* q3p = qbase + (size_t)q3*LDQK + g*8;
  const v8s qf0A = *(const v8s*)q0p, qf0B = *(const v8s*)(q0p + 32);
  const v8s qf1A = *(const v8s*)q1p, qf1B = *(const v8s*)(q1p + 32);
  const v8s qf2A = *(const v8s*)q2p, qf2B = *(const v8s*)(q2p + 32);
  const v8s qf3A = *(const v8s*)q3p, qf3B = *(const v8s*)(q3p + 32);

  float cj[8];
  #pragma unroll
  for (int j=0;j<4;++j){ cj[j] = (float)j * slope2; cj[4+j] = (float)(16+j) * slope2; }

  v4f oacc0[4], oacc1[4], oacc2[4], oacc3[4];
  #pragma unroll
  for (int nf=0;nf<4;++nf){
    oacc0[nf] = v4f_zero(); oacc1[nf] = v4f_zero();
    oacc2[nf] = v4f_zero(); oacc3[nf] = v4f_zero();
  }
  float l0 = 0.f, l1 = 0.f, l2 = 0.f, l3 = 0.f;

  v8s kf[4], kn[4], vf[4], vn[4];
  auto loadK = [&](v8s* d, const bf16* kp){
    d[0] = *(const v8s*)(kp);
    d[1] = *(const v8s*)(kp + 32);
    d[2] = *(const v8s*)(kp + (size_t)16*LDQK);
    d[3] = *(const v8s*)(kp + (size_t)16*LDQK + 32);
  };
  auto loadV = [&](v8s* d, const bf16* vp){
    #pragma unroll
    for (int nf=0;nf<4;++nf) d[nf] = *(const v8s*)(vp + (size_t)nf*16*LDVT);
  };

  auto processU = [&](const v8s& qfA, const v8s& qfB, int dd, bool last,
                      float& l, v4f* oa){
    v4f s0 = v4f_zero(), s1 = v4f_zero();
    __builtin_amdgcn_s_setprio(1);
    s0 = __builtin_amdgcn_mfma_f32_16x16x32_bf16(kf[0], qfA, s0, 0,0,0);
    s0 = __builtin_amdgcn_mfma_f32_16x16x32_bf16(kf[1], qfB, s0, 0,0,0);
    s1 = __builtin_amdgcn_mfma_f32_16x16x32_bf16(kf[2], qfA, s1, 0,0,0);
    s1 = __builtin_amdgcn_mfma_f32_16x16x32_bf16(kf[3], qfB, s1, 0,0,0);
    __builtin_amdgcn_s_setprio(0);
    const float base = (float)dd * slope2;
    float v[8];
    #pragma unroll
    for (int j=0;j<4;++j) v[j]   = fmaf(s0[j], scale2, base + cj[j]);
    #pragma unroll
    for (int j=0;j<4;++j) v[4+j] = fmaf(s1[j], scale2, base + cj[4+j]);
    if (last){
      #pragma unroll
      for (int j=0;j<4;++j){
        if (dd + j      > 0) v[j]   = -1e30f;
        if (dd + 16 + j > 0) v[4+j] = -1e30f;
      }
    }
    float p[8];
    #pragma unroll
    for (int j=0;j<8;++j){ p[j] = exp2f(v[j]); l += p[j]; }

    v2u lo; lo[0] = pack2t(p[0],p[1]); lo[1] = pack2t(p[2],p[3]);
    v2u hi; hi[0] = pack2t(p[4],p[5]); hi[1] = pack2t(p[6],p[7]);
    *(v2u*)&Psw[sp][r][g*4]      = lo;
    *(v2u*)&Psw[sp][r][16 + g*4] = hi;
    const v8s pf = *(const v8s*)&Psw[sp][r][g*8];

    __builtin_amdgcn_s_setprio(1);
    #pragma unroll
    for (int nf=0;nf<4;++nf)
      oa[nf] = __builtin_amdgcn_mfma_f32_16x16x32_bf16(vf[nf], pf, oa[nf], 0,0,0);
    __builtin_amdgcn_s_setprio(0);
  };

  const bf16* kp = kbase + (size_t)(sp*32 + r)*LDQK + g*8;
  const bf16* vp = vbase + (size_t)r*LDVT + sp*32 + g*8;
  int dd0 = sp*32 + g*4 - q0;
  int dd1 = sp*32 + g*4 - q1;
  int dd2 = sp*32 + g*4 - q2;
  int dd3 = sp*32 + g*4 - q3;

  loadK(kf, kp);
  loadV(vf, vp);
  for (int t = sp; t < nt3; t += 4){
    const bool more = (t+4 < nt3);
    if (more){
      loadK(kn, kp + (size_t)4*32*LDQK);
      loadV(vn, vp + 128);
    }

    processU(qf3A, qf3B, dd3, t == nt3-1, l3, oacc3);
    if (t < nt2) processU(qf2A, qf2B, dd2, t == nt2-1, l2, oacc2);
    if (t < nt1) processU(qf1A, qf1B, dd1, t == nt1-1, l1, oacc1);
    if (t < nt0) processU(qf0A, qf0B, dd0, t == nt0-1, l0, oacc0);

    if (more){
      #pragma unroll
      for (int i=0;i<4;++i){ kf[i] = kn[i]; vf[i] = vn[i]; }
      kp += (size_t)4*32*LDQK;
      vp += 128;
    }
    dd0 += 128; dd1 += 128; dd2 += 128; dd3 += 128;
  }

  // finalize deferred row-sums (reduce across the 4 g-groups; shfl only)
  l0 += __shfl_xor(l0, 16); l0 += __shfl_xor(l0, 32);
  l1 += __shfl_xor(l1, 16); l1 += __shfl_xor(l1, 32);
  l2 += __shfl_xor(l2, 16); l2 += __shfl_xor(l2, 32);
  l3 += __shfl_xor(l3, 16); l3 += __shfl_xor(l3, 32);

  if (g == 0){
    Ls[sp][0][r] = l0; Ls[sp][1][r] = l1;
    Ls[sp][2][r] = l2; Ls[sp][3][r] = l3;
  }

  // 4-phase split-K merge through ONE 16KB Os buffer; wave u merges subtile u
  auto merge = [&](int u, const int w){
    float L = 0.f;
    v4f O[4];
    #pragma unroll
    for (int nf=0;nf<4;++nf) O[nf] = v4f_zero();
    #pragma unroll
    for (int ss=0;ss<4;++ss){
      L += Ls[ss][u][r];
      #pragma unroll
      for (int nf=0;nf<4;++nf) O[nf] += Os[ss][nf][lane];
    }
    const float inv = 1.f/L;
    const int q = w*16 + r;
    bf16* orow = o + ((size_t)batch*2048 + q)*512 + head*64 + g*4;
    #pragma unroll
    for (int nf=0;nf<4;++nf){
      short4 st;
      st.x = f2b(O[nf][0]*inv);
      st.y = f2b(O[nf][1]*inv);
      st.z = f2b(O[nf][2]*inv);
      st.w = f2b(O[nf][3]*inv);
      *(short4*)(orow + nf*16) = st;
    }
  };

  #pragma unroll
  for (int nf=0;nf<4;++nf) Os[sp][nf][lane] = oacc0[nf];
  __syncthreads();
  if (sp == 0) merge(0, w0);
  __syncthreads();
  #pragma unroll
  for (int nf=0;nf<4;++nf) Os[sp][nf][lane] = oacc1[nf];
  __syncthreads();
  if (sp == 1) merge(1, w1);
  __syncthreads();
  #pragma unroll
  for (int nf=0;nf<4;++nf) Os[sp][nf][lane] = oacc2[nf];
  __syncthreads();
  if (sp == 2) merge(2, w2);
  __syncthreads();
  #pragma unroll
  for (int nf=0;nf<4;++nf) Os[sp][nf][lane] = oacc3[nf];
  __syncthreads();
  if (sp == 3) merge(3, w3);
}

// ---------------- orchestration ----------------
extern "C" void kernel_launch(void* const* d_in, const int* in_sizes, int n_in,
                              void* d_out, int out_size, void* d_ws, size_t ws_size,
                              hipStream_t stream)
{
  const float* x     = (const float*)d_in[0];
  const float* w_emb = (const float*)d_in[1];
  const float* b_emb = (const float*)d_in[2];
  const float* ln1_w = (const float*)d_in[3];
  const float* ln1_b = (const float*)d_in[4];
  const float* inp_w = (const float*)d_in[5];
  const float* inp_b = (const float*)d_in[6];
  const float* outp_w= (const float*)d_in[7];
  const float* outp_b= (const float*)d_in[8];
  const float* ln2_w = (const float*)d_in[9];
  const float* ln2_b = (const float*)d_in[10];
  const float* w1    = (const float*)d_in[11];
  const float* b1    = (const float*)d_in[12];
  const float* w2    = (const float*)d_in[13];
  const float* b2    = (const float*)d_in[14];
  const float* fln_w = (const float*)d_in[15];
  const float* fln_b = (const float*)d_in[16];
  const float* w_out = (const float*)d_in[17];
  const float* b_out = (const float*)d_in[18];

  char* wsp = (char*)d_ws;
  auto alloc = [&](size_t bytes){ void* p = (void*)wsp; wsp += (bytes + 255) & ~(size_t)255; return p; };
  float* h     = (float*)alloc(4096UL*512*4);
  bf16* xn     = (bf16*) alloc(4096UL*512*2);
  bf16* qkb    = (bf16*) alloc(4096UL*LDQK*2);
  bf16* vtb    = (bf16*) alloc(2UL*8*64*LDVT*2);
  bf16* ob     = (bf16*) alloc(4096UL*512*2);
  bf16* a1     = (bf16*) alloc(4096UL*2048*2);
  bf16* xbf    = (bf16*) alloc(4096UL*192*2);
  bf16* wembB  = (bf16*) alloc(512UL*192*2);
  bf16* inpwB  = (bf16*) alloc(4UL*1536*512*2);
  bf16* outpwB = (bf16*) alloc(4UL*512*512*2);
  bf16* w1B    = (bf16*) alloc(4UL*2048*512*2);
  bf16* w2B    = (bf16*) alloc(4UL*512*2048*2);
  bf16* woutB  = (bf16*) alloc(192UL*512*2);

  // one launch converts all fp32 inputs to bf16 (unpadded layouts)
  CvtArgs ca;
  ca.seg[0] = { x,      xbf,    (int)(4096UL*192/4)      };
  ca.seg[1] = { w_emb,  wembB,  (int)(512UL*192/4)       };
  ca.seg[2] = { inp_w,  inpwB,  (int)(4UL*1536*512/4)    };
  ca.seg[3] = { outp_w, outpwB, (int)(4UL*512*512/4)     };
  ca.seg[4] = { w1,     w1B,    (int)(4UL*2048*512/4)    };
  ca.seg[5] = { w2,     w2B,    (int)(4UL*512*2048/4)    };
  ca.seg[6] = { w_out,  woutB,  (int)(192UL*512/4)       };
  k_cvt7<<<dim3(256,7), dim3(256), 0, stream>>>(ca);

  // h = x @ w_emb.T + b_emb  (K=192 -> BK=32)
  k_gemm<32,128,32,1, EPI_F32><<<dim3(128,4), 256, 0, stream>>>(
      xbf, wembB, b_emb, h, nullptr, 4096, 512, 192, 512);

  for (int l=0; l<4; ++l){
    k_ln<<<dim3(1024), dim3(256), 0, stream>>>(h, ln1_w + l*512, ln1_b + l*512, xn);
    // fused QK+V projection (round-15 measured-best config)
    k_gemm<64,128,64,2, EPI_QKV><<<dim3(64,12), 256, 0, stream>>>(
        xn, inpwB + (size_t)l*1536*512, inp_b + l*1536, (float*)vtb, qkb,
        4096, 1536, 512, LDQK);
    k_attn<<<dim3(512), 256, 0, stream>>>(qkb, vtb, ob);
    // attn-out: measured-best BK=64 config
    k_gemm<32,128,64,1, EPI_F32RES><<<dim3(128,4), 256, 0, stream>>>(
        ob, outpwB + (size_t)l*512*512, outp_b + l*512, h, nullptr,
        4096, 512, 512, 512);
    k_ln<<<dim3(1024), dim3(256), 0, stream>>>(h, ln2_w + l*512, ln2_b + l*512, xn);
    // MLP up + GELU: BM=128/WR=2 -> 512 blocks (2/CU), 32 MFMA/wave/K-step
    k_gemm<128,128,64,2, EPI_GELU><<<dim3(32,16), 256, 0, stream>>>(
        xn, w1B + (size_t)l*2048*512, b1 + l*2048, nullptr, a1,
        4096, 2048, 512, 2048);
    // MLP down: measured-best BK=64 config
    k_gemm<32,128,64,1, EPI_F32RES><<<dim3(128,4), 256, 0, stream>>>(
        a1, w2B + (size_t)l*512*2048, b2 + l*512, h, nullptr,
        4096, 512, 2048, 512);
  }

  k_ln<<<dim3(1024), dim3(256), 0, stream>>>(h, fln_w, fln_b, xn);
  k_gemm<32,64,64,1, EPI_F32><<<dim3(128,3), 256, 0, stream>>>(
      xn, woutB, b_out, (float*)d_out, nullptr, 4096, 192, 512, 192);
}

// Round 21
// 534.145 us; speedup vs baseline: 1.0722x; 1.0722x over previous
//
#include <hip/hip_runtime.h>
#include <hip/hip_bf16.h>
#include <math.h>

typedef short v8s __attribute__((ext_vector_type(8)));
typedef float v4f __attribute__((ext_vector_type(4)));
typedef unsigned int v2u __attribute__((ext_vector_type(2)));
typedef __hip_bfloat16 bf16;

#define LDQK 1056   // qkb leading dim: 2112B row stride (breaks 2KB channel hotspot)
#define LDVT 2080   // vt row stride: 4160B (breaks 4KB)

__device__ inline short f2b(float f){
  __hip_bfloat16 h = __float2bfloat16(f);
  return __builtin_bit_cast(short, h);
}
// truncation pack for hot loop: P in [0,1], trunc error <= 2^-9 relative
__device__ inline unsigned int pack2t(float x, float y){
  unsigned int xb = __builtin_bit_cast(unsigned int, x);
  unsigned int yb = __builtin_bit_cast(unsigned int, y);
  return (xb >> 16) | (yb & 0xFFFF0000u);
}
__device__ inline v4f v4f_zero(){ v4f z = {0.f,0.f,0.f,0.f}; return z; }

__device__ inline void gload_lds16(const void* g, void* l){
  __builtin_amdgcn_global_load_lds(
      (__attribute__((address_space(1))) void*)(g),
      (__attribute__((address_space(3))) void*)(l), 16, 0, 0);
}

// ---------------- fp32 -> bf16 convert: all 7 tensors in ONE launch ----------------
struct CvtSeg { const float* s; bf16* d; int n4; };
struct CvtArgs { CvtSeg seg[7]; };

__global__ __launch_bounds__(256) void k_cvt7(CvtArgs a){
  const CvtSeg sg = a.seg[blockIdx.y];
  int i = blockIdx.x*256 + threadIdx.x;
  const int stride = gridDim.x*256;
  for (; i < sg.n4; i += stride){
    float4 v = ((const float4*)sg.s)[i];
    short4 o;
    o.x = f2b(v.x); o.y = f2b(v.y); o.z = f2b(v.z); o.w = f2b(v.w);
    ((short4*)sg.d)[i] = o;
  }
}

// ---------------- LayerNorm: one wave per row of 512, fp32 in -> bf16 out ----------------
__global__ __launch_bounds__(256) void k_ln(const float* __restrict__ x,
                                            const float* __restrict__ w,
                                            const float* __restrict__ b,
                                            bf16* __restrict__ out){
  const int row  = blockIdx.x*4 + (threadIdx.x>>6);
  const int lane = threadIdx.x & 63;
  const float* xr = x + (size_t)row*512 + lane*8;
  float4 a = *(const float4*)xr;
  float4 c = *(const float4*)(xr+4);
  float s  = a.x+a.y+a.z+a.w + c.x+c.y+c.z+c.w;
  float sq = a.x*a.x+a.y*a.y+a.z*a.z+a.w*a.w + c.x*c.x+c.y*c.y+c.z*c.z+c.w*c.w;
  #pragma unroll
  for (int m=1;m<64;m<<=1){ s += __shfl_xor(s,m); sq += __shfl_xor(sq,m); }
  const float mean = s*(1.f/512.f);
  const float rstd = rsqrtf(sq*(1.f/512.f) - mean*mean + 1e-5f);
  const float* wp = w + lane*8; const float* bp = b + lane*8;
  float4 w0 = *(const float4*)wp, w1v = *(const float4*)(wp+4);
  float4 b0 = *(const float4*)bp, b1v = *(const float4*)(bp+4);
  v8s o;
  o[0]=f2b((a.x-mean)*rstd*w0.x +b0.x);
  o[1]=f2b((a.y-mean)*rstd*w0.y +b0.y);
  o[2]=f2b((a.z-mean)*rstd*w0.z +b0.z);
  o[3]=f2b((a.w-mean)*rstd*w0.w +b0.w);
  o[4]=f2b((c.x-mean)*rstd*w1v.x+b1v.x);
  o[5]=f2b((c.y-mean)*rstd*w1v.y+b1v.y);
  o[6]=f2b((c.z-mean)*rstd*w1v.z+b1v.z);
  o[7]=f2b((c.w-mean)*rstd*w1v.w+b1v.w);
  *(v8s*)(out + (size_t)row*512 + lane*8) = o;
}

// ---------------- GEMM: C[M,N] = A[M,K] * W[N,K]^T + bias, fused epilogues ----------------
enum { EPI_F32=0, EPI_BF16=1, EPI_F32RES=2, EPI_GELU=3, EPI_VT=4, EPI_QKV=5 };

template<int BM, int BN, int BK, int WR, int EPI>
__global__ __launch_bounds__(256) void k_gemm(
    const bf16* __restrict__ A, const bf16* __restrict__ W,
    const float* __restrict__ bias,
    float* __restrict__ resf, bf16* __restrict__ outb,
    const int M, const int N, const int K, const int ldo)
{
  constexpr int WC = 4/WR;
  constexpr int FM = BM/(WR*16);
  constexpr int FN = BN/(WC*16);
  constexpr int KK = BK/32;
  constexpr int CPR = BK/8;             // 16B chunks per row of a K-step
  __shared__ __align__(16) bf16 As[2][BM*BK];
  __shared__ __align__(16) bf16 Bs[2][BN*BK];
  const int tid  = threadIdx.x;
  const int wave = tid>>6, lane = tid&63;
  const int r = lane&15, g = lane>>4;
  const int bm = blockIdx.x*BM, bn = blockIdx.y*BN;
  const int wr = (WR==1) ? 0 : (wave>>1);
  const int wc = (WR==1) ? wave : (wave&1);

  v4f acc[FM][FN];
  #pragma unroll
  for (int i=0;i<FM;++i)
    #pragma unroll
    for (int j=0;j<FN;++j) acc[i][j] = v4f_zero();

  const int NT = K / BK;

  auto stage = [&](int buf, int kb){
    constexpr int ACH = BM*CPR;
    #pragma unroll
    for (int it=0; it<(ACH+255)/256; ++it){
      const int cb = it*256 + wave*64;
      if ((ACH & 255) == 0 || cb < ACH){
        const int cc = cb + lane;
        const bf16* gp = A + (size_t)(bm + cc/CPR)*K + kb + (cc%CPR)*8;
        gload_lds16(gp, &As[buf][cc*8]);
      }
    }
    constexpr int BCH = BN*CPR;
    #pragma unroll
    for (int it=0; it<(BCH+255)/256; ++it){
      const int cb = it*256 + wave*64;
      if ((BCH & 255) == 0 || cb < BCH){
        const int cc = cb + lane;
        const bf16* gp = W + (size_t)(bn + cc/CPR)*K + kb + (cc%CPR)*8;
        gload_lds16(gp, &Bs[buf][cc*8]);
      }
    }
  };

  stage(0, 0);
  int cur = 0;
  for (int t=0; t<NT; ++t){
    __syncthreads();
    if (t+1 < NT) stage(cur^1, (t+1)*BK);
    const bf16* ap = &As[cur][(wr*(BM/WR) + r)*BK + g*8];
    const bf16* bp = &Bs[cur][(wc*(BN/WC) + r)*BK + g*8];
    #pragma unroll
    for (int kk=0; kk<KK; ++kk){
      v8s af[FM], bfr[FN];
      #pragma unroll
      for (int i=0;i<FM;++i) af[i] = *(const v8s*)(ap + i*16*BK + kk*32);
      #pragma unroll
      for (int j=0;j<FN;++j) bfr[j] = *(const v8s*)(bp + j*16*BK + kk*32);
      #pragma unroll
      for (int i=0;i<FM;++i)
        #pragma unroll
        for (int j=0;j<FN;++j)
          acc[i][j] = __builtin_amdgcn_mfma_f32_16x16x32_bf16(af[i], bfr[j], acc[i][j], 0,0,0);
    }
    cur ^= 1;
  }

  #pragma unroll
  for (int j=0;j<FN;++j){
    const int col = bn + wc*(BN/WC) + j*16 + r;
    const float bv = bias[col];
    #pragma unroll
    for (int i=0;i<FM;++i){
      const int row0 = bm + wr*(BM/WR) + i*16 + g*4;
      if constexpr (EPI==EPI_QKV){
        // fused QK+V projection: cols 0..1023 -> qkb (padded LDQK rows),
        // cols 1024..1535 -> Vt[b][h][d][s] (row stride LDVT). resf = (float*)vtb.
        if (col < 1024){
          #pragma unroll
          for (int q=0;q<4;++q)
            outb[(size_t)(row0+q)*LDQK + col] = __float2bfloat16(acc[i][j][q] + bv);
        } else {
          const int d = col - 1024;
          bf16* vt = (bf16*)resf
                   + (((size_t)(row0>>11)*8 + (d>>6))*64 + (d&63))*(size_t)LDVT + (row0&2047);
          short4 st;
          st.x = f2b(acc[i][j][0] + bv);
          st.y = f2b(acc[i][j][1] + bv);
          st.z = f2b(acc[i][j][2] + bv);
          st.w = f2b(acc[i][j][3] + bv);
          *(short4*)vt = st;
        }
      } else if constexpr (EPI==EPI_VT){
        bf16* vt = outb + (((size_t)(row0>>11)*8 + (col>>6))*64 + (col&63))*(size_t)ldo + (row0&2047);
        short4 st;
        st.x = f2b(acc[i][j][0] + bv);
        st.y = f2b(acc[i][j][1] + bv);
        st.z = f2b(acc[i][j][2] + bv);
        st.w = f2b(acc[i][j][3] + bv);
        *(short4*)vt = st;
      } else {
        #pragma unroll
        for (int q=0;q<4;++q){
          float v = acc[i][j][q] + bv;
          const size_t idx = (size_t)(row0+q)*ldo + col;
          if constexpr (EPI==EPI_F32)         resf[idx] = v;
          else if constexpr (EPI==EPI_F32RES) resf[idx] += v;
          else if constexpr (EPI==EPI_BF16)   outb[idx] = __float2bfloat16(v);
          else if constexpr (EPI==EPI_GELU){
            float gv = 0.5f*v*(1.f + erff(v*0.70710678118654752f));
            outb[idx] = __float2bfloat16(gv);
          }
        }
      }
    }
  }
}

// ---------------- causal + ALiBi flash attention (round-12 verified: padded strides, fixed-max) ----------------
// qk: [B,S,LDQK], vt: [B,NH,64,LDVT], o: [B,S,512]
// 1D grid 1024: flat = qi*16 + b*8 + h -> XCD(flat%8)=h (per-head L2 locality).
// Block = q-tile pair (qi, 127-qi); wave sp takes k-tiles t = sp, sp+4, ...
// Fixed-max softmax (exact: scores << exp2 overflow; ALiBi <= 0 underflows to 0).
// K AND V register-double-buffered. P packed by truncation (pack2t).
__global__ __launch_bounds__(256) void k_attn(const bf16* __restrict__ qk,
                                              const bf16* __restrict__ vt,
                                              bf16* __restrict__ o){
  const int flat  = blockIdx.x;
  const int qi    = flat >> 4;
  const int head  = flat & 7;
  const int batch = (flat >> 3) & 1;
  const int sp = threadIdx.x>>6, lane = threadIdx.x&63;
  const int r = lane&15, g = lane>>4;
  const float LOG2E = 1.4426950408889634f;
  const float scale2 = 0.125f * LOG2E;
  const float slope2 = exp2f(-(float)(head+1)) * LOG2E;
  const bf16* qbase = qk + (size_t)batch*2048*LDQK + head*64;
  const bf16* kbase = qbase + 512;
  const bf16* vbase = vt + (size_t)(batch*8 + head)*64*LDVT;

  __shared__ float Ls[4][2][16];
  __shared__ __align__(16) v4f Os[4][2][4][64];
  __shared__ __align__(16) short Psw[4][16][40];   // padded: row stride 80B

  const int w0 = qi, w1 = 127-qi;
  const int nt0 = (w0>>1) + 1;
  const int nt1 = (w1>>1) + 1;
  const int q0 = w0*16 + r, q1 = w1*16 + r;

  const bf16* q0p = qbase + (size_t)q0*LDQK + g*8;
  const bf16* q1p = qbase + (size_t)q1*LDQK + g*8;
  const v8s qf0A = *(const v8s*)q0p, qf0B = *(const v8s*)(q0p + 32);
  const v8s qf1A = *(const v8s*)q1p, qf1B = *(const v8s*)(q1p + 32);

  float cj[8];
  #pragma unroll
  for (int j=0;j<4;++j){ cj[j] = (float)j * slope2; cj[4+j] = (float)(16+j) * slope2; }

  v4f oacc0[4], oacc1[4];
  #pragma unroll
  for (int nf=0;nf<4;++nf){ oacc0[nf] = v4f_zero(); oacc1[nf] = v4f_zero(); }
  float l0 = 0.f, l1 = 0.f;

  v8s kf[4], kn[4], vf[4], vn[4];
  auto loadK = [&](v8s* d, const bf16* kp){
    d[0] = *(const v8s*)(kp);
    d[1] = *(const v8s*)(kp + 32);
    d[2] = *(const v8s*)(kp + (size_t)16*LDQK);
    d[3] = *(const v8s*)(kp + (size_t)16*LDQK + 32);
  };
  auto loadV = [&](v8s* d, const bf16* vp){
    #pragma unroll
    for (int nf=0;nf<4;++nf) d[nf] = *(const v8s*)(vp + (size_t)nf*16*LDVT);
  };

  auto processU = [&](const v8s& qfA, const v8s& qfB, int dd, bool last,
                      float& l, v4f* oa){
    v4f s0 = v4f_zero(), s1 = v4f_zero();
    s0 = __builtin_amdgcn_mfma_f32_16x16x32_bf16(kf[0], qfA, s0, 0,0,0);
    s0 = __builtin_amdgcn_mfma_f32_16x16x32_bf16(kf[1], qfB, s0, 0,0,0);
    s1 = __builtin_amdgcn_mfma_f32_16x16x32_bf16(kf[2], qfA, s1, 0,0,0);
    s1 = __builtin_amdgcn_mfma_f32_16x16x32_bf16(kf[3], qfB, s1, 0,0,0);
    const float base = (float)dd * slope2;
    float v[8];
    #pragma unroll
    for (int j=0;j<4;++j) v[j]   = fmaf(s0[j], scale2, base + cj[j]);
    #pragma unroll
    for (int j=0;j<4;++j) v[4+j] = fmaf(s1[j], scale2, base + cj[4+j]);
    if (last){
      #pragma unroll
      for (int j=0;j<4;++j){
        if (dd + j      > 0) v[j]   = -1e30f;
        if (dd + 16 + j > 0) v[4+j] = -1e30f;
      }
    }
    // fixed-max softmax: p = exp2(v) directly; masked -> exp2(-1e30) = 0
    float p[8];
    #pragma unroll
    for (int j=0;j<8;++j){ p[j] = exp2f(v[j]); l += p[j]; }

    v2u lo; lo[0] = pack2t(p[0],p[1]); lo[1] = pack2t(p[2],p[3]);
    v2u hi; hi[0] = pack2t(p[4],p[5]); hi[1] = pack2t(p[6],p[7]);
    *(v2u*)&Psw[sp][r][g*4]      = lo;
    *(v2u*)&Psw[sp][r][16 + g*4] = hi;
    const v8s pf = *(const v8s*)&Psw[sp][r][g*8];

    #pragma unroll
    for (int nf=0;nf<4;++nf)
      oa[nf] = __builtin_amdgcn_mfma_f32_16x16x32_bf16(vf[nf], pf, oa[nf], 0,0,0);
  };

  const bf16* kp = kbase + (size_t)(sp*32 + r)*LDQK + g*8;
  const bf16* vp = vbase + (size_t)r*LDVT + sp*32 + g*8;
  int dd0 = sp*32 + g*4 - q0;
  int dd1 = sp*32 + g*4 - q1;

  loadK(kf, kp);
  loadV(vf, vp);
  for (int t = sp; t < nt1; t += 4){
    const bool more = (t+4 < nt1);
    if (more){
      loadK(kn, kp + (size_t)4*32*LDQK);
      loadV(vn, vp + 128);
    }

    processU(qf1A, qf1B, dd1, t == nt1-1, l1, oacc1);
    if (t < nt0)
      processU(qf0A, qf0B, dd0, t == nt0-1, l0, oacc0);

    if (more){
      #pragma unroll
      for (int i=0;i<4;++i){ kf[i] = kn[i]; vf[i] = vn[i]; }
      kp += (size_t)4*32*LDQK;
      vp += 128;
    }
    dd0 += 128; dd1 += 128;
  }

  l0 += __shfl_xor(l0, 16); l0 += __shfl_xor(l0, 32);
  l1 += __shfl_xor(l1, 16); l1 += __shfl_xor(l1, 32);

  if (g == 0){
    Ls[sp][0][r] = l0;
    Ls[sp][1][r] = l1;
  }
  #pragma unroll
  for (int nf=0;nf<4;++nf){ Os[sp][0][nf][lane] = oacc0[nf]; Os[sp][1][nf][lane] = oacc1[nf]; }
  __syncthreads();

  if (sp < 2){
    const int u = sp;
    const int w = u ? w1 : w0;
    float L = 0.f;
    v4f O[4];
    #pragma unroll
    for (int nf=0;nf<4;++nf) O[nf] = v4f_zero();
    #pragma unroll
    for (int ss=0;ss<4;++ss){
      L += Ls[ss][u][r];
      #pragma unroll
      for (int nf=0;nf<4;++nf) O[nf] += Os[ss][u][nf][lane];
    }
    const float inv = 1.f/L;
    const int q = w*16 + r;
    bf16* orow = o + ((size_t)batch*2048 + q)*512 + head*64 + g*4;
    #pragma unroll
    for (int nf=0;nf<4;++nf){
      short4 st;
      st.x = f2b(O[nf][0]*inv);
      st.y = f2b(O[nf][1]*inv);
      st.z = f2b(O[nf][2]*inv);
      st.w = f2b(O[nf][3]*inv);
      *(short4*)(orow + nf*16) = st;
    }
  }
}

// ---------------- orchestration ----------------
extern "C" void kernel_launch(void* const* d_in, const int* in_sizes, int n_in,
                              void* d_out, int out_size, void* d_ws, size_t ws_size,
                              hipStream_t stream)
{
  const float* x     = (const float*)d_in[0];
  const float* w_emb = (const float*)d_in[1];
  const float* b_emb = (const float*)d_in[2];
  const float* ln1_w = (const float*)d_in[3];
  const float* ln1_b = (const float*)d_in[4];
  const float* inp_w = (const float*)d_in[5];
  const float* inp_b = (const float*)d_in[6];
  const float* outp_w= (const float*)d_in[7];
  const float* outp_b= (const float*)d_in[8];
  const float* ln2_w = (const float*)d_in[9];
  const float* ln2_b = (const float*)d_in[10];
  const float* w1    = (const float*)d_in[11];
  const float* b1    = (const float*)d_in[12];
  const float* w2    = (const float*)d_in[13];
  const float* b2    = (const float*)d_in[14];
  const float* fln_w = (const float*)d_in[15];
  const float* fln_b = (const float*)d_in[16];
  const float* w_out = (const float*)d_in[17];
  const float* b_out = (const float*)d_in[18];

  char* wsp = (char*)d_ws;
  auto alloc = [&](size_t bytes){ void* p = (void*)wsp; wsp += (bytes + 255) & ~(size_t)255; return p; };
  float* h     = (float*)alloc(4096UL*512*4);
  bf16* xn     = (bf16*) alloc(4096UL*512*2);
  bf16* qkb    = (bf16*) alloc(4096UL*LDQK*2);
  bf16* vtb    = (bf16*) alloc(2UL*8*64*LDVT*2);
  bf16* ob     = (bf16*) alloc(4096UL*512*2);
  bf16* a1     = (bf16*) alloc(4096UL*2048*2);
  bf16* xbf    = (bf16*) alloc(4096UL*192*2);
  bf16* wembB  = (bf16*) alloc(512UL*192*2);
  bf16* inpwB  = (bf16*) alloc(4UL*1536*512*2);
  bf16* outpwB = (bf16*) alloc(4UL*512*512*2);
  bf16* w1B    = (bf16*) alloc(4UL*2048*512*2);
  bf16* w2B    = (bf16*) alloc(4UL*512*2048*2);
  bf16* woutB  = (bf16*) alloc(192UL*512*2);

  // one launch converts all fp32 inputs to bf16 (unpadded layouts)
  CvtArgs ca;
  ca.seg[0] = { x,      xbf,    (int)(4096UL*192/4)      };
  ca.seg[1] = { w_emb,  wembB,  (int)(512UL*192/4)       };
  ca.seg[2] = { inp_w,  inpwB,  (int)(4UL*1536*512/4)    };
  ca.seg[3] = { outp_w, outpwB, (int)(4UL*512*512/4)     };
  ca.seg[4] = { w1,     w1B,    (int)(4UL*2048*512/4)    };
  ca.seg[5] = { w2,     w2B,    (int)(4UL*512*2048/4)    };
  ca.seg[6] = { w_out,  woutB,  (int)(192UL*512/4)       };
  k_cvt7<<<dim3(256,7), dim3(256), 0, stream>>>(ca);

  // h = x @ w_emb.T + b_emb  (K=192 -> BK=32)
  k_gemm<32,128,32,1, EPI_F32><<<dim3(128,4), 256, 0, stream>>>(
      xbf, wembB, b_emb, h, nullptr, 4096, 512, 192, 512);

  for (int l=0; l<4; ++l){
    k_ln<<<dim3(1024), dim3(256), 0, stream>>>(h, ln1_w + l*512, ln1_b + l*512, xn);
    // fused QK+V projection: BM=64/WR=2 -> 768 blocks (3/CU), 16 MFMA/wave/K-step
    k_gemm<64,128,64,2, EPI_QKV><<<dim3(64,12), 256, 0, stream>>>(
        xn, inpwB + (size_t)l*1536*512, inp_b + l*1536, (float*)vtb, qkb,
        4096, 1536, 512, LDQK);
    k_attn<<<dim3(1024), 256, 0, stream>>>(qkb, vtb, ob);
    // attn-out: measured-best BK=64 config
    k_gemm<32,128,64,1, EPI_F32RES><<<dim3(128,4), 256, 0, stream>>>(
        ob, outpwB + (size_t)l*512*512, outp_b + l*512, h, nullptr,
        4096, 512, 512, 512);
    k_ln<<<dim3(1024), dim3(256), 0, stream>>>(h, ln2_w + l*512, ln2_b + l*512, xn);
    // MLP up + GELU: BM=128/WR=2 -> 512 blocks (2/CU), 32 MFMA/wave/K-step
    k_gemm<128,128,64,2, EPI_GELU><<<dim3(32,16), 256, 0, stream>>>(
        xn, w1B + (size_t)l*2048*512, b1 + l*2048, nullptr, a1,
        4096, 2048, 512, 2048);
    // MLP down: measured-best BK=64 config
    k_gemm<32,128,64,1, EPI_F32RES><<<dim3(128,4), 256, 0, stream>>>(
        a1, w2B + (size_t)l*512*2048, b2 + l*512, h, nullptr,
        4096, 512, 2048, 512);
  }

  k_ln<<<dim3(1024), dim3(256), 0, stream>>>(h, fln_w, fln_b, xn);
  k_gemm<32,64,64,1, EPI_F32><<<dim3(128,3), 256, 0, stream>>>(
      xn, woutB, b_out, (float*)d_out, nullptr, 4096, 192, 512, 192);
}

// Round 22
// 516.691 us; speedup vs baseline: 1.1085x; 1.0338x over previous
//
#include <hip/hip_runtime.h>
#include <hip/hip_bf16.h>
#include <math.h>

typedef short v8s __attribute__((ext_vector_type(8)));
typedef float v4f __attribute__((ext_vector_type(4)));
typedef unsigned int v2u __attribute__((ext_vector_type(2)));
typedef __hip_bfloat16 bf16;

#define LDQK 1056   // qkb leading dim: 2112B row stride (breaks 2KB channel hotspot)
#define LDVT 2080   // vt row stride: 4160B (breaks 4KB)

__device__ inline short f2b(float f){
  __hip_bfloat16 h = __float2bfloat16(f);
  return __builtin_bit_cast(short, h);
}
// truncation pack for hot loop: P in [0,1], trunc error <= 2^-9 relative
__device__ inline unsigned int pack2t(float x, float y){
  unsigned int xb = __builtin_bit_cast(unsigned int, x);
  unsigned int yb = __builtin_bit_cast(unsigned int, y);
  return (xb >> 16) | (yb & 0xFFFF0000u);
}
__device__ inline v4f v4f_zero(){ v4f z = {0.f,0.f,0.f,0.f}; return z; }

__device__ inline void gload_lds16(const void* g, void* l){
  __builtin_amdgcn_global_load_lds(
      (__attribute__((address_space(1))) void*)(g),
      (__attribute__((address_space(3))) void*)(l), 16, 0, 0);
}

// ---------------- fp32 -> bf16 convert: all 7 tensors in ONE launch ----------------
struct CvtSeg { const float* s; bf16* d; int n4; };
struct CvtArgs { CvtSeg seg[7]; };

__global__ __launch_bounds__(256) void k_cvt7(CvtArgs a){
  const CvtSeg sg = a.seg[blockIdx.y];
  int i = blockIdx.x*256 + threadIdx.x;
  const int stride = gridDim.x*256;
  for (; i < sg.n4; i += stride){
    float4 v = ((const float4*)sg.s)[i];
    short4 o;
    o.x = f2b(v.x); o.y = f2b(v.y); o.z = f2b(v.z); o.w = f2b(v.w);
    ((short4*)sg.d)[i] = o;
  }
}

// ---------------- LayerNorm: one wave per row of 512, fp32 in -> bf16 out ----------------
__global__ __launch_bounds__(256) void k_ln(const float* __restrict__ x,
                                            const float* __restrict__ w,
                                            const float* __restrict__ b,
                                            bf16* __restrict__ out){
  const int row  = blockIdx.x*4 + (threadIdx.x>>6);
  const int lane = threadIdx.x & 63;
  const float* xr = x + (size_t)row*512 + lane*8;
  float4 a = *(const float4*)xr;
  float4 c = *(const float4*)(xr+4);
  float s  = a.x+a.y+a.z+a.w + c.x+c.y+c.z+c.w;
  float sq = a.x*a.x+a.y*a.y+a.z*a.z+a.w*a.w + c.x*c.x+c.y*c.y+c.z*c.z+c.w*c.w;
  #pragma unroll
  for (int m=1;m<64;m<<=1){ s += __shfl_xor(s,m); sq += __shfl_xor(sq,m); }
  const float mean = s*(1.f/512.f);
  const float rstd = rsqrtf(sq*(1.f/512.f) - mean*mean + 1e-5f);
  const float* wp = w + lane*8; const float* bp = b + lane*8;
  float4 w0 = *(const float4*)wp, w1v = *(const float4*)(wp+4);
  float4 b0 = *(const float4*)bp, b1v = *(const float4*)(bp+4);
  v8s o;
  o[0]=f2b((a.x-mean)*rstd*w0.x +b0.x);
  o[1]=f2b((a.y-mean)*rstd*w0.y +b0.y);
  o[2]=f2b((a.z-mean)*rstd*w0.z +b0.z);
  o[3]=f2b((a.w-mean)*rstd*w0.w +b0.w);
  o[4]=f2b((c.x-mean)*rstd*w1v.x+b1v.x);
  o[5]=f2b((c.y-mean)*rstd*w1v.y+b1v.y);
  o[6]=f2b((c.z-mean)*rstd*w1v.z+b1v.z);
  o[7]=f2b((c.w-mean)*rstd*w1v.w+b1v.w);
  *(v8s*)(out + (size_t)row*512 + lane*8) = o;
}

// ---------------- GEMM: C[M,N] = A[M,K] * W[N,K]^T + bias, fused epilogues ----------------
// SK>1: split-K across blockIdx.z; residual epilogue uses atomicAdd, bias added by z==0 only.
enum { EPI_F32=0, EPI_BF16=1, EPI_F32RES=2, EPI_GELU=3, EPI_VT=4, EPI_QKV=5 };

template<int BM, int BN, int BK, int WR, int EPI, int SK=1>
__global__ __launch_bounds__(256) void k_gemm(
    const bf16* __restrict__ A, const bf16* __restrict__ W,
    const float* __restrict__ bias,
    float* __restrict__ resf, bf16* __restrict__ outb,
    const int M, const int N, const int K, const int ldo)
{
  constexpr int WC = 4/WR;
  constexpr int FM = BM/(WR*16);
  constexpr int FN = BN/(WC*16);
  constexpr int KK = BK/32;
  constexpr int CPR = BK/8;             // 16B chunks per row of a K-step
  __shared__ __align__(16) bf16 As[2][BM*BK];
  __shared__ __align__(16) bf16 Bs[2][BN*BK];
  const int tid  = threadIdx.x;
  const int wave = tid>>6, lane = tid&63;
  const int r = lane&15, g = lane>>4;
  const int bm = blockIdx.x*BM, bn = blockIdx.y*BN;
  const int wr = (WR==1) ? 0 : (wave>>1);
  const int wc = (WR==1) ? wave : (wave&1);

  const int kz = (SK>1) ? (int)blockIdx.z : 0;
  const int Ke = K / SK;
  const bf16* Ab = A + (size_t)kz*Ke;
  const bf16* Wb = W + (size_t)kz*Ke;

  v4f acc[FM][FN];
  #pragma unroll
  for (int i=0;i<FM;++i)
    #pragma unroll
    for (int j=0;j<FN;++j) acc[i][j] = v4f_zero();

  const int NT = Ke / BK;

  auto stage = [&](int buf, int kb){
    constexpr int ACH = BM*CPR;
    #pragma unroll
    for (int it=0; it<(ACH+255)/256; ++it){
      const int cb = it*256 + wave*64;
      if ((ACH & 255) == 0 || cb < ACH){
        const int cc = cb + lane;
        const bf16* gp = Ab + (size_t)(bm + cc/CPR)*K + kb + (cc%CPR)*8;
        gload_lds16(gp, &As[buf][cc*8]);
      }
    }
    constexpr int BCH = BN*CPR;
    #pragma unroll
    for (int it=0; it<(BCH+255)/256; ++it){
      const int cb = it*256 + wave*64;
      if ((BCH & 255) == 0 || cb < BCH){
        const int cc = cb + lane;
        const bf16* gp = Wb + (size_t)(bn + cc/CPR)*K + kb + (cc%CPR)*8;
        gload_lds16(gp, &Bs[buf][cc*8]);
      }
    }
  };

  stage(0, 0);
  int cur = 0;
  for (int t=0; t<NT; ++t){
    __syncthreads();
    if (t+1 < NT) stage(cur^1, (t+1)*BK);
    const bf16* ap = &As[cur][(wr*(BM/WR) + r)*BK + g*8];
    const bf16* bp = &Bs[cur][(wc*(BN/WC) + r)*BK + g*8];
    #pragma unroll
    for (int kk=0; kk<KK; ++kk){
      v8s af[FM], bfr[FN];
      #pragma unroll
      for (int i=0;i<FM;++i) af[i] = *(const v8s*)(ap + i*16*BK + kk*32);
      #pragma unroll
      for (int j=0;j<FN;++j) bfr[j] = *(const v8s*)(bp + j*16*BK + kk*32);
      #pragma unroll
      for (int i=0;i<FM;++i)
        #pragma unroll
        for (int j=0;j<FN;++j)
          acc[i][j] = __builtin_amdgcn_mfma_f32_16x16x32_bf16(af[i], bfr[j], acc[i][j], 0,0,0);
    }
    cur ^= 1;
  }

  #pragma unroll
  for (int j=0;j<FN;++j){
    const int col = bn + wc*(BN/WC) + j*16 + r;
    const float bv = (SK>1 && kz != 0) ? 0.f : bias[col];
    #pragma unroll
    for (int i=0;i<FM;++i){
      const int row0 = bm + wr*(BM/WR) + i*16 + g*4;
      if constexpr (EPI==EPI_QKV){
        // fused QK+V projection: cols 0..1023 -> qkb (padded LDQK rows),
        // cols 1024..1535 -> Vt[b][h][d][s] (row stride LDVT). resf = (float*)vtb.
        if (col < 1024){
          #pragma unroll
          for (int q=0;q<4;++q)
            outb[(size_t)(row0+q)*LDQK + col] = __float2bfloat16(acc[i][j][q] + bv);
        } else {
          const int d = col - 1024;
          bf16* vt = (bf16*)resf
                   + (((size_t)(row0>>11)*8 + (d>>6))*64 + (d&63))*(size_t)LDVT + (row0&2047);
          short4 st;
          st.x = f2b(acc[i][j][0] + bv);
          st.y = f2b(acc[i][j][1] + bv);
          st.z = f2b(acc[i][j][2] + bv);
          st.w = f2b(acc[i][j][3] + bv);
          *(short4*)vt = st;
        }
      } else if constexpr (EPI==EPI_VT){
        bf16* vt = outb + (((size_t)(row0>>11)*8 + (col>>6))*64 + (col&63))*(size_t)ldo + (row0&2047);
        short4 st;
        st.x = f2b(acc[i][j][0] + bv);
        st.y = f2b(acc[i][j][1] + bv);
        st.z = f2b(acc[i][j][2] + bv);
        st.w = f2b(acc[i][j][3] + bv);
        *(short4*)vt = st;
      } else {
        #pragma unroll
        for (int q=0;q<4;++q){
          float v = acc[i][j][q] + bv;
          const size_t idx = (size_t)(row0+q)*ldo + col;
          if constexpr (EPI==EPI_F32)         resf[idx] = v;
          else if constexpr (EPI==EPI_F32RES){
            if constexpr (SK>1) atomicAdd(&resf[idx], v);
            else                resf[idx] += v;
          }
          else if constexpr (EPI==EPI_BF16)   outb[idx] = __float2bfloat16(v);
          else if constexpr (EPI==EPI_GELU){
            float gv = 0.5f*v*(1.f + erff(v*0.70710678118654752f));
            outb[idx] = __float2bfloat16(gv);
          }
        }
      }
    }
  }
}

// ---------------- causal + ALiBi flash attention (round-12 verified: padded strides, fixed-max) ----------------
// qk: [B,S,LDQK], vt: [B,NH,64,LDVT], o: [B,S,512]
// 1D grid 1024: flat = qi*16 + b*8 + h -> XCD(flat%8)=h (per-head L2 locality).
// Block = q-tile pair (qi, 127-qi); wave sp takes k-tiles t = sp, sp+4, ...
// Fixed-max softmax (exact: scores << exp2 overflow; ALiBi <= 0 underflows to 0).
// K AND V register-double-buffered. P packed by truncation (pack2t).
__global__ __launch_bounds__(256) void k_attn(const bf16* __restrict__ qk,
                                              const bf16* __restrict__ vt,
                                              bf16* __restrict__ o){
  const int flat  = blockIdx.x;
  const int qi    = flat >> 4;
  const int head  = flat & 7;
  const int batch = (flat >> 3) & 1;
  const int sp = threadIdx.x>>6, lane = threadIdx.x&63;
  const int r = lane&15, g = lane>>4;
  const float LOG2E = 1.4426950408889634f;
  const float scale2 = 0.125f * LOG2E;
  const float slope2 = exp2f(-(float)(head+1)) * LOG2E;
  const bf16* qbase = qk + (size_t)batch*2048*LDQK + head*64;
  const bf16* kbase = qbase + 512;
  const bf16* vbase = vt + (size_t)(batch*8 + head)*64*LDVT;

  __shared__ float Ls[4][2][16];
  __shared__ __align__(16) v4f Os[4][2][4][64];
  __shared__ __align__(16) short Psw[4][16][40];   // padded: row stride 80B

  const int w0 = qi, w1 = 127-qi;
  const int nt0 = (w0>>1) + 1;
  const int nt1 = (w1>>1) + 1;
  const int q0 = w0*16 + r, q1 = w1*16 + r;

  const bf16* q0p = qbase + (size_t)q0*LDQK + g*8;
  const bf16* q1p = qbase + (size_t)q1*LDQK + g*8;
  const v8s qf0A = *(const v8s*)q0p, qf0B = *(const v8s*)(q0p + 32);
  const v8s qf1A = *(const v8s*)q1p, qf1B = *(const v8s*)(q1p + 32);

  float cj[8];
  #pragma unroll
  for (int j=0;j<4;++j){ cj[j] = (float)j * slope2; cj[4+j] = (float)(16+j) * slope2; }

  v4f oacc0[4], oacc1[4];
  #pragma unroll
  for (int nf=0;nf<4;++nf){ oacc0[nf] = v4f_zero(); oacc1[nf] = v4f_zero(); }
  float l0 = 0.f, l1 = 0.f;

  v8s kf[4], kn[4], vf[4], vn[4];
  auto loadK = [&](v8s* d, const bf16* kp){
    d[0] = *(const v8s*)(kp);
    d[1] = *(const v8s*)(kp + 32);
    d[2] = *(const v8s*)(kp + (size_t)16*LDQK);
    d[3] = *(const v8s*)(kp + (size_t)16*LDQK + 32);
  };
  auto loadV = [&](v8s* d, const bf16* vp){
    #pragma unroll
    for (int nf=0;nf<4;++nf) d[nf] = *(const v8s*)(vp + (size_t)nf*16*LDVT);
  };

  auto processU = [&](const v8s& qfA, const v8s& qfB, int dd, bool last,
                      float& l, v4f* oa){
    v4f s0 = v4f_zero(), s1 = v4f_zero();
    s0 = __builtin_amdgcn_mfma_f32_16x16x32_bf16(kf[0], qfA, s0, 0,0,0);
    s0 = __builtin_amdgcn_mfma_f32_16x16x32_bf16(kf[1], qfB, s0, 0,0,0);
    s1 = __builtin_amdgcn_mfma_f32_16x16x32_bf16(kf[2], qfA, s1, 0,0,0);
    s1 = __builtin_amdgcn_mfma_f32_16x16x32_bf16(kf[3], qfB, s1, 0,0,0);
    const float base = (float)dd * slope2;
    float v[8];
    #pragma unroll
    for (int j=0;j<4;++j) v[j]   = fmaf(s0[j], scale2, base + cj[j]);
    #pragma unroll
    for (int j=0;j<4;++j) v[4+j] = fmaf(s1[j], scale2, base + cj[4+j]);
    if (last){
      #pragma unroll
      for (int j=0;j<4;++j){
        if (dd + j      > 0) v[j]   = -1e30f;
        if (dd + 16 + j > 0) v[4+j] = -1e30f;
      }
    }
    // fixed-max softmax: p = exp2(v) directly; masked -> exp2(-1e30) = 0
    float p[8];
    #pragma unroll
    for (int j=0;j<8;++j){ p[j] = exp2f(v[j]); l += p[j]; }

    v2u lo; lo[0] = pack2t(p[0],p[1]); lo[1] = pack2t(p[2],p[3]);
    v2u hi; hi[0] = pack2t(p[4],p[5]); hi[1] = pack2t(p[6],p[7]);
    *(v2u*)&Psw[sp][r][g*4]      = lo;
    *(v2u*)&Psw[sp][r][16 + g*4] = hi;
    const v8s pf = *(const v8s*)&Psw[sp][r][g*8];

    #pragma unroll
    for (int nf=0;nf<4;++nf)
      oa[nf] = __builtin_amdgcn_mfma_f32_16x16x32_bf16(vf[nf], pf, oa[nf], 0,0,0);
  };

  const bf16* kp = kbase + (size_t)(sp*32 + r)*LDQK + g*8;
  const bf16* vp = vbase + (size_t)r*LDVT + sp*32 + g*8;
  int dd0 = sp*32 + g*4 - q0;
  int dd1 = sp*32 + g*4 - q1;

  loadK(kf, kp);
  loadV(vf, vp);
  for (int t = sp; t < nt1; t += 4){
    const bool more = (t+4 < nt1);
    if (more){
      loadK(kn, kp + (size_t)4*32*LDQK);
      loadV(vn, vp + 128);
    }

    processU(qf1A, qf1B, dd1, t == nt1-1, l1, oacc1);
    if (t < nt0)
      processU(qf0A, qf0B, dd0, t == nt0-1, l0, oacc0);

    if (more){
      #pragma unroll
      for (int i=0;i<4;++i){ kf[i] = kn[i]; vf[i] = vn[i]; }
      kp += (size_t)4*32*LDQK;
      vp += 128;
    }
    dd0 += 128; dd1 += 128;
  }

  l0 += __shfl_xor(l0, 16); l0 += __shfl_xor(l0, 32);
  l1 += __shfl_xor(l1, 16); l1 += __shfl_xor(l1, 32);

  if (g == 0){
    Ls[sp][0][r] = l0;
    Ls[sp][1][r] = l1;
  }
  #pragma unroll
  for (int nf=0;nf<4;++nf){ Os[sp][0][nf][lane] = oacc0[nf]; Os[sp][1][nf][lane] = oacc1[nf]; }
  __syncthreads();

  if (sp < 2){
    const int u = sp;
    const int w = u ? w1 : w0;
    float L = 0.f;
    v4f O[4];
    #pragma unroll
    for (int nf=0;nf<4;++nf) O[nf] = v4f_zero();
    #pragma unroll
    for (int ss=0;ss<4;++ss){
      L += Ls[ss][u][r];
      #pragma unroll
      for (int nf=0;nf<4;++nf) O[nf] += Os[ss][u][nf][lane];
    }
    const float inv = 1.f/L;
    const int q = w*16 + r;
    bf16* orow = o + ((size_t)batch*2048 + q)*512 + head*64 + g*4;
    #pragma unroll
    for (int nf=0;nf<4;++nf){
      short4 st;
      st.x = f2b(O[nf][0]*inv);
      st.y = f2b(O[nf][1]*inv);
      st.z = f2b(O[nf][2]*inv);
      st.w = f2b(O[nf][3]*inv);
      *(short4*)(orow + nf*16) = st;
    }
  }
}

// ---------------- orchestration ----------------
extern "C" void kernel_launch(void* const* d_in, const int* in_sizes, int n_in,
                              void* d_out, int out_size, void* d_ws, size_t ws_size,
                              hipStream_t stream)
{
  const float* x     = (const float*)d_in[0];
  const float* w_emb = (const float*)d_in[1];
  const float* b_emb = (const float*)d_in[2];
  const float* ln1_w = (const float*)d_in[3];
  const float* ln1_b = (const float*)d_in[4];
  const float* inp_w = (const float*)d_in[5];
  const float* inp_b = (const float*)d_in[6];
  const float* outp_w= (const float*)d_in[7];
  const float* outp_b= (const float*)d_in[8];
  const float* ln2_w = (const float*)d_in[9];
  const float* ln2_b = (const float*)d_in[10];
  const float* w1    = (const float*)d_in[11];
  const float* b1    = (const float*)d_in[12];
  const float* w2    = (const float*)d_in[13];
  const float* b2    = (const float*)d_in[14];
  const float* fln_w = (const float*)d_in[15];
  const float* fln_b = (const float*)d_in[16];
  const float* w_out = (const float*)d_in[17];
  const float* b_out = (const float*)d_in[18];

  char* wsp = (char*)d_ws;
  auto alloc = [&](size_t bytes){ void* p = (void*)wsp; wsp += (bytes + 255) & ~(size_t)255; return p; };
  float* h     = (float*)alloc(4096UL*512*4);
  bf16* xn     = (bf16*) alloc(4096UL*512*2);
  bf16* qkb    = (bf16*) alloc(4096UL*LDQK*2);
  bf16* vtb    = (bf16*) alloc(2UL*8*64*LDVT*2);
  bf16* ob     = (bf16*) alloc(4096UL*512*2);
  bf16* a1     = (bf16*) alloc(4096UL*2048*2);
  bf16* xbf    = (bf16*) alloc(4096UL*192*2);
  bf16* wembB  = (bf16*) alloc(512UL*192*2);
  bf16* inpwB  = (bf16*) alloc(4UL*1536*512*2);
  bf16* outpwB = (bf16*) alloc(4UL*512*512*2);
  bf16* w1B    = (bf16*) alloc(4UL*2048*512*2);
  bf16* w2B    = (bf16*) alloc(4UL*512*2048*2);
  bf16* woutB  = (bf16*) alloc(192UL*512*2);

  // one launch converts all fp32 inputs to bf16 (unpadded layouts)
  CvtArgs ca;
  ca.seg[0] = { x,      xbf,    (int)(4096UL*192/4)      };
  ca.seg[1] = { w_emb,  wembB,  (int)(512UL*192/4)       };
  ca.seg[2] = { inp_w,  inpwB,  (int)(4UL*1536*512/4)    };
  ca.seg[3] = { outp_w, outpwB, (int)(4UL*512*512/4)     };
  ca.seg[4] = { w1,     w1B,    (int)(4UL*2048*512/4)    };
  ca.seg[5] = { w2,     w2B,    (int)(4UL*512*2048/4)    };
  ca.seg[6] = { w_out,  woutB,  (int)(192UL*512/4)       };
  k_cvt7<<<dim3(256,7), dim3(256), 0, stream>>>(ca);

  // h = x @ w_emb.T + b_emb  (K=192 -> BK=32)
  k_gemm<32,128,32,1, EPI_F32><<<dim3(128,4), 256, 0, stream>>>(
      xbf, wembB, b_emb, h, nullptr, 4096, 512, 192, 512);

  for (int l=0; l<4; ++l){
    k_ln<<<dim3(1024), dim3(256), 0, stream>>>(h, ln1_w + l*512, ln1_b + l*512, xn);
    // fused QK+V projection: BM=64/WR=2 -> 768 blocks (3/CU), 16 MFMA/wave/K-step
    k_gemm<64,128,64,2, EPI_QKV><<<dim3(64,12), 256, 0, stream>>>(
        xn, inpwB + (size_t)l*1536*512, inp_b + l*1536, (float*)vtb, qkb,
        4096, 1536, 512, LDQK);
    k_attn<<<dim3(1024), 256, 0, stream>>>(qkb, vtb, ob);
    // attn-out: measured-best BK=64 config
    k_gemm<32,128,64,1, EPI_F32RES><<<dim3(128,4), 256, 0, stream>>>(
        ob, outpwB + (size_t)l*512*512, outp_b + l*512, h, nullptr,
        4096, 512, 512, 512);
    k_ln<<<dim3(1024), dim3(256), 0, stream>>>(h, ln2_w + l*512, ln2_b + l*512, xn);
    // MLP up + GELU: BM=128/WR=2 -> 512 blocks (2/CU), 32 MFMA/wave/K-step
    k_gemm<128,128,64,2, EPI_GELU><<<dim3(32,16), 256, 0, stream>>>(
        xn, w1B + (size_t)l*2048*512, b1 + l*2048, nullptr, a1,
        4096, 2048, 512, 2048);
    // MLP down: split-K=2 across blockIdx.z -> NT 32->16, 1024 blocks (4/CU);
    // residual merge via atomicAdd (2 adders/element, bias from z==0 only)
    k_gemm<32,128,64,1, EPI_F32RES,2><<<dim3(128,4,2), 256, 0, stream>>>(
        a1, w2B + (size_t)l*512*2048, b2 + l*512, h, nullptr,
        4096, 512, 2048, 512);
  }

  k_ln<<<dim3(1024), dim3(256), 0, stream>>>(h, fln_w, fln_b, xn);
  k_gemm<32,64,64,1, EPI_F32><<<dim3(128,3), 256, 0, stream>>>(
      xn, woutB, b_out, (float*)d_out, nullptr, 4096, 192, 512, 192);
}